// Round 9
// baseline (122.972 us; speedup 1.0000x reference)
//
#include <hip/hip_runtime.h>

typedef float f4 __attribute__((ext_vector_type(4)));

#define BB 32
#define CC 512
#define LL 4096
#define NB 16
#define EPSF 1e-8f

// ---------------- fused main kernel: barrier-free, ONE read of x ----------
// (R5 hot loop — best measured.) grid = 32 b x 16 chunks = 512 blocks
// (2/CU). Wave w owns channels c0+8w..8w+7; lane holds l = 256i+4*lane+k.
// Tail: 4-wave LDS fold, then fire-and-forget atomicAdd into the FINAL
// 2 MiB dot/ss accumulators (no 16 MiB partial round-trip).
__global__ __launch_bounds__(256, 2)
void k_main(const float* __restrict__ x, float* __restrict__ g,
            float* __restrict__ dacc, float* __restrict__ sacc) {
    __shared__ f4 ldsD[1024], ldsS[1024];    // 32 KB
    const int tid = threadIdx.x;
    const int w = tid >> 6, lane = tid & 63;
    const int b  = blockIdx.x >> 4;
    const int c0 = (blockIdx.x & 15) * 32;

    f4 dA[16], sA[16];
#pragma unroll
    for (int i = 0; i < 16; ++i) { dA[i] = (f4)0.f; sA[i] = (f4)0.f; }

    const f4* base = (const f4*)(x + ((size_t)b * CC + c0 + w * 8) * LL);
    for (int cc = 0; cc < 8; ++cc) {
        const f4* row = base + (size_t)cc * 1024;
        f4 v[16];
#pragma unroll
        for (int i = 0; i < 16; ++i) v[i] = row[i * 64 + lane];
        float s = 0.f;
#pragma unroll
        for (int i = 0; i < 16; ++i) s += (v[i][0] + v[i][1]) + (v[i][2] + v[i][3]);
#pragma unroll
        for (int off = 32; off; off >>= 1) s += __shfl_down(s, off, 64);
        s = __shfl(s, 0, 64);                // broadcast
        const float gv = s * (1.0f / LL);
        if (lane == 0) g[b * CC + c0 + w * 8 + cc] = gv;
#pragma unroll
        for (int i = 0; i < 16; ++i) {
#pragma unroll
            for (int k = 0; k < 4; ++k) {
                dA[i][k] = fmaf(v[i][k], gv, dA[i][k]);
                sA[i][k] = fmaf(v[i][k], v[i][k], sA[i][k]);
            }
        }
    }
    // 4-step wave combine (cuts atomic count 4x)
    for (int ww = 0; ww < 4; ++ww) {
        if (w == ww) {
#pragma unroll
            for (int i = 0; i < 16; ++i) {
                const int idx = i * 64 + lane;
                if (ww == 0) { ldsD[idx] = dA[i];  ldsS[idx] = sA[i]; }
                else         { ldsD[idx] += dA[i]; ldsS[idx] += sA[i]; }
            }
        }
        __syncthreads();
    }
    // quad slot s = j*256+tid covers l = 4s..4s+3 -> linear float layout
#pragma unroll
    for (int j = 0; j < 4; ++j) {
        const int s = j * 256 + tid;
        f4 dv = ldsD[s], sv = ldsS[s];
        float* dp = dacc + (size_t)b * LL + 4 * s;
        float* sp = sacc + (size_t)b * LL + 4 * s;
#pragma unroll
        for (int k = 0; k < 4; ++k) {
            atomicAdd(dp + k, dv[k]);
            atomicAdd(sp + k, sv[k]);
        }
    }
}

// ---------------- fused reduce + hist: 32 blocks x 1024 threads -----------
// Block b reads its FINAL dot/ss (32 KB, L2/L3-hot) -> cos in regs ->
// per-b min/max -> release+arrive -> spin till 32 blocks -> global range ->
// bin own 4 values -> block reduce -> normalize -> write out.
// 32 blocks on 256 CUs are always co-resident -> spin cannot deadlock.
__global__ __launch_bounds__(1024, 1)
void k_rh(const float* __restrict__ g,
          const f4* __restrict__ dacc4, const f4* __restrict__ sacc4,
          float* __restrict__ pmin, float* __restrict__ pmax,
          unsigned* __restrict__ counter, float* __restrict__ out) {
    const int b = blockIdx.x;
    const int tid = threadIdx.x;            // one quad slot each
    const int w = tid >> 6, lane = tid & 63;

    f4 pdv = dacc4[(size_t)b * 1024 + tid];
    f4 psv = sacc4[(size_t)b * 1024 + tid];

    // gn per wave (redundant, L2-hot)
    const f4* g4p = (const f4*)(g + b * CC);
    f4 ga = g4p[lane], gb2 = g4p[64 + lane];
    float sq = 0.f;
#pragma unroll
    for (int k = 0; k < 4; ++k) sq = fmaf(ga[k], ga[k], fmaf(gb2[k], gb2[k], sq));
#pragma unroll
    for (int off = 32; off; off >>= 1) sq += __shfl_down(sq, off, 64);
    const float gn = sqrtf(__shfl(sq, 0, 64));

    f4 cs;
#pragma unroll
    for (int k = 0; k < 4; ++k)
        cs[k] = pdv[k] / fmaxf(sqrtf(psv[k]) * gn, EPSF);

    // per-b min/max
    float mn = fminf(fminf(cs[0], cs[1]), fminf(cs[2], cs[3]));
    float mx = fmaxf(fmaxf(cs[0], cs[1]), fmaxf(cs[2], cs[3]));
#pragma unroll
    for (int off = 32; off; off >>= 1) {
        mn = fminf(mn, __shfl_down(mn, off, 64));
        mx = fmaxf(mx, __shfl_down(mx, off, 64));
    }
    __shared__ float smn[16], smx[16];
    if (lane == 0) { smn[w] = mn; smx[w] = mx; }
    __syncthreads();
    if (tid == 0) {
        float bmn = smn[0], bmx = smx[0];
#pragma unroll
        for (int i = 1; i < 16; ++i) { bmn = fminf(bmn, smn[i]); bmx = fmaxf(bmx, smx[i]); }
        pmin[b] = bmn; pmax[b] = bmx;
        __threadfence();                     // release pmin/pmax
        atomicAdd(counter, 1u);              // arrive (device scope)
    }
    if (tid == 0) {
        while (__hip_atomic_load(counter, __ATOMIC_ACQUIRE, __HIP_MEMORY_SCOPE_AGENT) < 32u)
            __builtin_amdgcn_s_sleep(2);
    }
    __syncthreads();

    // global min/max over 32 blocks
    __shared__ float lmn[32], lmx[32];
    if (tid < 32) {
        lmn[tid] = __hip_atomic_load(&pmin[tid], __ATOMIC_RELAXED, __HIP_MEMORY_SCOPE_AGENT);
        lmx[tid] = __hip_atomic_load(&pmax[tid], __ATOMIC_RELAXED, __HIP_MEMORY_SCOPE_AGENT);
    }
    __syncthreads();
    float gmn = lmn[0], gmx = lmx[0];
#pragma unroll
    for (int i = 1; i < 32; ++i) { gmn = fminf(gmn, lmn[i]); gmx = fmaxf(gmx, lmx[i]); }
    const float range = gmx - gmn;

    // histogram of this thread's 4 cos values
    float bins[NB];
#pragma unroll
    for (int n = 0; n < NB; ++n) bins[n] = 0.f;
#pragma unroll
    for (int k = 0; k < 4; ++k) {
        const float s = cs[k];
#pragma unroll
        for (int n = 0; n < NB; ++n) {
            float lev = gmn + ((float)n * range) / 15.0f;   // match ref order of ops
            float d = fabsf(s - lev);
            bins[n] += (d < 0.03125f) ? (1.0f - d) : 0.f;
        }
    }
#pragma unroll
    for (int n = 0; n < NB; ++n) {
#pragma unroll
        for (int off = 32; off; off >>= 1) bins[n] += __shfl_down(bins[n], off, 64);
    }
    __shared__ float sb[16][NB];
    if (lane == 0) {
#pragma unroll
        for (int n = 0; n < NB; ++n) sb[w][n] = bins[n];
    }
    __syncthreads();
    __shared__ float colsum[NB];
    if (tid < NB) {
        float c = 0.f;
#pragma unroll
        for (int i = 0; i < 16; ++i) c += sb[i][tid];
        colsum[tid] = c;
    }
    __syncthreads();
    if (tid < NB * 32) {
        float total = 0.f;
#pragma unroll
        for (int n = 0; n < NB; ++n) total += colsum[n];
        out[b * (NB * 32) + tid] = colsum[tid >> 5] / total;
    }
}

extern "C" void kernel_launch(void* const* d_in, const int* in_sizes, int n_in,
                              void* d_out, int out_size, void* d_ws, size_t ws_size,
                              hipStream_t stream) {
    const float* x = (const float*)d_in[0];
    float* out = (float*)d_out;
    float* ws  = (float*)d_ws;

    float*    g       = ws;                        // 16384 floats
    float*    dacc    = ws + 16384;                // 131072 floats (B*L)
    float*    sacc    = dacc + 131072;             // 131072 floats
    unsigned* counter = (unsigned*)(sacc + 131072);
    float*    pmin    = (float*)(counter + 16);    // 32
    float*    pmax    = pmin + 32;                 // 32

    // zero dacc+sacc+counter in one contiguous memset (graph-capturable)
    hipMemsetAsync(dacc, 0, (2 * 131072) * sizeof(float) + 64, stream);
    k_main<<<512, 256, 0, stream>>>(x, g, dacc, sacc);
    k_rh<<<32, 1024, 0, stream>>>(g, (const f4*)dacc, (const f4*)sacc,
                                  pmin, pmax, counter, out);
}

// Round 10
// 112.797 us; speedup vs baseline: 1.0902x; 1.0902x over previous
//
#include <hip/hip_runtime.h>

typedef float f4 __attribute__((ext_vector_type(4)));

#define BB 32
#define CC 512
#define LL 4096
#define NB 16
#define EPSF 1e-8f

// ---------------- fused main kernel: barrier-free, ONE read of x ----------
// (R5 structure — best measured, unchanged.)
__global__ __launch_bounds__(256, 2)
void k_main(const float* __restrict__ x, float* __restrict__ g,
            f4* __restrict__ pd4, f4* __restrict__ ps4) {
    __shared__ f4 ldsD[1024], ldsS[1024];    // 32 KB
    const int tid = threadIdx.x;
    const int w = tid >> 6, lane = tid & 63;
    const int b  = blockIdx.x >> 4;
    const int c0 = (blockIdx.x & 15) * 32;

    f4 dA[16], sA[16];
#pragma unroll
    for (int i = 0; i < 16; ++i) { dA[i] = (f4)0.f; sA[i] = (f4)0.f; }

    const f4* base = (const f4*)(x + ((size_t)b * CC + c0 + w * 8) * LL);
    for (int cc = 0; cc < 8; ++cc) {
        const f4* row = base + (size_t)cc * 1024;
        f4 v[16];
#pragma unroll
        for (int i = 0; i < 16; ++i) v[i] = row[i * 64 + lane];
        float s = 0.f;
#pragma unroll
        for (int i = 0; i < 16; ++i) s += (v[i][0] + v[i][1]) + (v[i][2] + v[i][3]);
#pragma unroll
        for (int off = 32; off; off >>= 1) s += __shfl_down(s, off, 64);
        s = __shfl(s, 0, 64);                // broadcast
        const float gv = s * (1.0f / LL);
        if (lane == 0) g[b * CC + c0 + w * 8 + cc] = gv;
#pragma unroll
        for (int i = 0; i < 16; ++i) {
#pragma unroll
            for (int k = 0; k < 4; ++k) {
                dA[i][k] = fmaf(v[i][k], gv, dA[i][k]);
                sA[i][k] = fmaf(v[i][k], v[i][k], sA[i][k]);
            }
        }
    }
    for (int ww = 0; ww < 4; ++ww) {
        if (w == ww) {
#pragma unroll
            for (int i = 0; i < 16; ++i) {
                const int idx = i * 64 + lane;
                if (ww == 0) { ldsD[idx] = dA[i];  ldsS[idx] = sA[i]; }
                else         { ldsD[idx] += dA[i]; ldsS[idx] += sA[i]; }
            }
        }
        __syncthreads();
    }
#pragma unroll
    for (int j = 0; j < 4; ++j) {
        pd4[(size_t)blockIdx.x * 1024 + j * 256 + tid] = ldsD[j * 256 + tid];
        ps4[(size_t)blockIdx.x * 1024 + j * 256 + tid] = ldsS[j * 256 + tid];
    }
}

// ------- fused reduce + hist: 512 blocks x 256 thr, 2-phase spin barrier ---
// Phase 1 = R5's k_reduce fold (full 512-block BW). cos stays in wave-0
// registers (no cosv HBM round-trip). Barrier 1 -> global range. Bin own
// 256 values -> per-block bins (64 B, no float atomics). Barrier 2 ->
// 32 survivor blocks fold 16 bin-vectors in fixed order, normalize, write.
// k_rh is register/LDS-light -> many blocks/CU possible; 512 blocks are
// always co-resident on 256 CUs -> spins cannot deadlock.
__global__ __launch_bounds__(256)
void k_rh(const float* __restrict__ g,
          const f4* __restrict__ pd4, const f4* __restrict__ ps4,
          float* __restrict__ pmin, float* __restrict__ pmax,
          float* __restrict__ bblk, unsigned* __restrict__ counters,
          float* __restrict__ out) {
    const int tid = threadIdx.x;
    const int w = tid >> 6, lane = tid & 63;
    const int b = blockIdx.x >> 4;
    const int sl = (blockIdx.x & 15) * 64 + lane;   // quad slot within b

    // ---- phase 1: fold chunk partials (identical to R5 k_reduce) ----
    f4 pdv = (f4)0.f, psv = (f4)0.f;
    const size_t cb = (size_t)b * 16;
#pragma unroll
    for (int c = 0; c < 4; ++c) {
        const int ch = 4 * w + c;
        pdv += pd4[((cb + ch) << 10) + sl];
        psv += ps4[((cb + ch) << 10) + sl];
    }
    __shared__ f4 sD[4][64], sS[4][64];
    sD[w][lane] = pdv;
    sS[w][lane] = psv;

    const f4* g4p = (const f4*)(g + b * CC);
    f4 ga = g4p[lane], gb2 = g4p[64 + lane];
    float sq = 0.f;
#pragma unroll
    for (int k = 0; k < 4; ++k) sq = fmaf(ga[k], ga[k], fmaf(gb2[k], gb2[k], sq));
#pragma unroll
    for (int off = 32; off; off >>= 1) sq += __shfl_down(sq, off, 64);
    const float gn = sqrtf(__shfl(sq, 0, 64));

    __syncthreads();
    f4 cs = (f4)0.f;
    float mn = 1e30f, mx = -1e30f;
    if (tid < 64) {
        f4 d = ((sD[0][lane] + sD[1][lane]) + sD[2][lane]) + sD[3][lane];
        f4 ssum = ((sS[0][lane] + sS[1][lane]) + sS[2][lane]) + sS[3][lane];
#pragma unroll
        for (int k = 0; k < 4; ++k)
            cs[k] = d[k] / fmaxf(sqrtf(ssum[k]) * gn, EPSF);
        mn = fminf(fminf(cs[0], cs[1]), fminf(cs[2], cs[3]));
        mx = fmaxf(fmaxf(cs[0], cs[1]), fmaxf(cs[2], cs[3]));
#pragma unroll
        for (int off = 32; off; off >>= 1) {
            mn = fminf(mn, __shfl_down(mn, off, 64));
            mx = fmaxf(mx, __shfl_down(mx, off, 64));
        }
    }
    if (tid == 0) {
        pmin[blockIdx.x] = mn;
        pmax[blockIdx.x] = mx;
        __threadfence();                     // release pmin/pmax
        atomicAdd(&counters[0], 1u);         // arrive 1
        while (__hip_atomic_load(&counters[0], __ATOMIC_ACQUIRE, __HIP_MEMORY_SCOPE_AGENT) < 512u)
            __builtin_amdgcn_s_sleep(2);
    }
    __syncthreads();

    // ---- global min/max over 512 block partials (L2-hot, redundant) ----
    float m0 = fminf(pmin[tid], pmin[tid + 256]);
    float m1 = fmaxf(pmax[tid], pmax[tid + 256]);
#pragma unroll
    for (int off = 32; off; off >>= 1) {
        m0 = fminf(m0, __shfl_down(m0, off, 64));
        m1 = fmaxf(m1, __shfl_down(m1, off, 64));
    }
    __shared__ float smn[4], smx[4];
    if (lane == 0) { smn[w] = m0; smx[w] = m1; }
    __syncthreads();
    const float gmn = fminf(fminf(smn[0], smn[1]), fminf(smn[2], smn[3]));
    const float gmx = fmaxf(fmaxf(smx[0], smx[1]), fmaxf(smx[2], smx[3]));
    const float range = gmx - gmn;

    // ---- bin this block's 256 cos values (held in wave 0's registers) ----
    if (tid < 64) {
        float bins[NB];
#pragma unroll
        for (int n = 0; n < NB; ++n) bins[n] = 0.f;
#pragma unroll
        for (int k = 0; k < 4; ++k) {
            const float s = cs[k];
#pragma unroll
            for (int n = 0; n < NB; ++n) {
                float lev = gmn + ((float)n * range) / 15.0f;   // ref order of ops
                float d = fabsf(s - lev);
                bins[n] += (d < 0.03125f) ? (1.0f - d) : 0.f;
            }
        }
#pragma unroll
        for (int n = 0; n < NB; ++n) {
#pragma unroll
            for (int off = 32; off; off >>= 1) bins[n] += __shfl_down(bins[n], off, 64);
        }
        if (lane == 0) {
#pragma unroll
            for (int n = 0; n < NB; ++n) bblk[blockIdx.x * NB + n] = bins[n];
            __threadfence();                 // release bblk
            atomicAdd(&counters[1], 1u);     // arrive 2
        }
    }
    if ((blockIdx.x & 15) != 0) return;      // 32 survivor blocks continue

    if (tid == 0) {
        while (__hip_atomic_load(&counters[1], __ATOMIC_ACQUIRE, __HIP_MEMORY_SCOPE_AGENT) < 512u)
            __builtin_amdgcn_s_sleep(2);
    }
    __syncthreads();

    // ---- fold 16 chunk-bin-vectors (fixed ascending order), normalize ----
    __shared__ float colsum[NB];
    if (tid < NB) {
        float c = 0.f;
#pragma unroll
        for (int ch = 0; ch < 16; ++ch)
            c += bblk[(b * 16 + ch) * NB + tid];
        colsum[tid] = c;
    }
    __syncthreads();
    float total = 0.f;
#pragma unroll
    for (int n = 0; n < NB; ++n) total += colsum[n];
    {
        const int i0 = tid;
        out[b * (NB * 32) + i0]       = colsum[i0 >> 5] / total;
        out[b * (NB * 32) + i0 + 256] = colsum[(i0 + 256) >> 5] / total;
    }
}

extern "C" void kernel_launch(void* const* d_in, const int* in_sizes, int n_in,
                              void* d_out, int out_size, void* d_ws, size_t ws_size,
                              hipStream_t stream) {
    const float* x = (const float*)d_in[0];
    float* out = (float*)d_out;
    float* ws  = (float*)d_ws;

    float*    g        = ws;                         // 16384 floats
    float*    pmin     = ws + 16384;                 // 512
    float*    pmax     = pmin + 512;                 // 512
    unsigned* counters = (unsigned*)(pmax + 512);    // 16 uints
    float*    bblk     = (float*)(counters + 16);    // 512*16 floats
    f4*       pd4      = (f4*)(bblk + 8192);         // 512 blocks * 1024 f4
    f4*       ps4      = pd4 + 524288;               // 8 MiB each

    hipMemsetAsync(counters, 0, 64, stream);
    k_main<<<512, 256, 0, stream>>>(x, g, pd4, ps4);
    k_rh<<<512, 256, 0, stream>>>(g, pd4, ps4, pmin, pmax, bblk,
                                  counters, out);
}